// Round 5
// baseline (216.732 us; speedup 1.0000x reference)
//
#include <hip/hip_runtime.h>
#include <math.h>
#include <float.h>

#define N_ROWS 65536
#define K_CODES 1024
#define C_DIM 64
#define BLK 256
#define TMARGIN 0.02f

typedef short s16x8 __attribute__((ext_vector_type(8)));
typedef float f32x4 __attribute__((ext_vector_type(4)));

// d_out layout (float32), outputs concatenated in return order:
// [loss(1)][quantized_st(N*C)][perplexity(1)][indices(N)][avg_probs(K)]
#define OUT_LOSS 0
#define OUT_Q 1
#define OUT_PPL (1 + N_ROWS * C_DIM)     // 4194305
#define OUT_IDX (OUT_PPL + 1)            // 4194306
#define OUT_AVG (OUT_IDX + N_ROWS)       // 4259842

// d_ws layout (4-byte units)
#define WS_HIST 0                        // uint[1024]
#define WS_EE 1024                       // float[1024]
#define WS_LOSSP 2048                    // float[256]
#define WS_QC 2304                       // uint[1] refine-queue count
#define WS_IDX 4096                      // int[N_ROWS] final indices
#define WS_QROWS (WS_IDX + N_ROWS)       // int[N_ROWS] refine queue
#define WS_BS (WS_QROWS + N_ROWS)        // ushort[K_CODES*128] split codebook

__device__ __forceinline__ unsigned short bf16_rne(float f) {
    unsigned u = __float_as_uint(f);
    return (unsigned short)((u + 0x7FFFu + ((u >> 16) & 1u)) >> 16);
}
__device__ __forceinline__ float bf16_val(unsigned short h) {
    return __uint_as_float(((unsigned)h) << 16);
}

// Kernel A: zero hist, reset queue, ||e||^2 (verified order), split codebook
__global__ void vq_prep(const float* __restrict__ emb, float* __restrict__ ee,
                        unsigned* __restrict__ hist,
                        unsigned short* __restrict__ bs,
                        unsigned* __restrict__ qc) {
    int k = blockIdx.x * BLK + threadIdx.x;
    if (k == 0) *qc = 0u;
    if (k < K_CODES) {
        hist[k] = 0u;
        const float* ev = emb + (size_t)k * C_DIM;
        float s0 = 0.f, s1 = 0.f, s2 = 0.f, s3 = 0.f;
#pragma unroll
        for (int i = 0; i < 16; ++i) {
            float a = ev[4 * i + 0], b = ev[4 * i + 1];
            float c = ev[4 * i + 2], d = ev[4 * i + 3];
            s0 = fmaf(a, a, s0);
            s1 = fmaf(b, b, s1);
            s2 = fmaf(c, c, s2);
            s3 = fmaf(d, d, s3);
        }
        ee[k] = (s0 + s1) + (s2 + s3);
        // split e = eh + em (bf16 RNE twice); layout [code][eh 0..63 | em 0..63]
#pragma unroll 8
        for (int c = 0; c < C_DIM; ++c) {
            float e = ev[c];
            unsigned short h = bf16_rne(e);
            float m = e - bf16_val(h);
            bs[(size_t)k * 128 + c] = h;
            bs[(size_t)k * 128 + 64 + c] = bf16_rne(m);
        }
    }
}

// Kernel B: MFMA distances (3-term bf16 split), per-row top-2 + argmin,
// margin-based refine queue. No LDS, B streams from L2.
__global__ __launch_bounds__(BLK, 4) void vq_mfma(
    const float* __restrict__ x, const unsigned short* __restrict__ bs,
    const float* __restrict__ ee, int* __restrict__ idxout,
    unsigned* __restrict__ qcount, int* __restrict__ qrows) {
    const int wave = threadIdx.x >> 6;
    const int lane = threadIdx.x & 63;
    const int lrow = lane & 15;          // A-row / C-col lane index
    const int lq = lane >> 4;            // 0..3 : k-quarter / C row-group
    const int rowbase = blockIdx.x * 64 + wave * 16;
    const int myrow = rowbase + lrow;

    // ---- A fragments: load 2x8 fp32 of my row, split to bf16 h/m, pack ----
    const float* xp = x + (size_t)myrow * C_DIM + lq * 8;
    float a0[8], a1[8];
#pragma unroll
    for (int j = 0; j < 8; ++j) { a0[j] = xp[j]; a1[j] = xp[32 + j]; }

    s16x8 xh0, xh1, xm0, xm1;
#pragma unroll
    for (int j = 0; j < 8; ++j) {
        unsigned short h0 = bf16_rne(a0[j]);
        unsigned short h1 = bf16_rne(a1[j]);
        xh0[j] = (short)h0;
        xh1[j] = (short)h1;
        xm0[j] = (short)bf16_rne(a0[j] - bf16_val(h0));
        xm1[j] = (short)bf16_rne(a1[j] - bf16_val(h1));
    }

    float b1[4], b2[4];
    int i1[4];
#pragma unroll
    for (int q = 0; q < 4; ++q) { b1[q] = FLT_MAX; b2[q] = FLT_MAX; i1[q] = 0; }

    for (int t = 0; t < K_CODES / 16; ++t) {
        const int code = t * 16 + lrow;
        const unsigned short* bp = bs + (size_t)code * 128 + lq * 8;
        s16x8 beh0 = *(const s16x8*)(bp);        // eh, k 0..31 slice
        s16x8 beh1 = *(const s16x8*)(bp + 32);   // eh, k 32..63 slice
        s16x8 bem0 = *(const s16x8*)(bp + 64);   // em, k 0..31 slice
        s16x8 bem1 = *(const s16x8*)(bp + 96);   // em, k 32..63 slice
        float eek = ee[code];

        f32x4 acc = {0.f, 0.f, 0.f, 0.f};
        acc = __builtin_amdgcn_mfma_f32_16x16x32_bf16(xh0, beh0, acc, 0, 0, 0);
        acc = __builtin_amdgcn_mfma_f32_16x16x32_bf16(xh1, beh1, acc, 0, 0, 0);
        acc = __builtin_amdgcn_mfma_f32_16x16x32_bf16(xh0, bem0, acc, 0, 0, 0);
        acc = __builtin_amdgcn_mfma_f32_16x16x32_bf16(xh1, bem1, acc, 0, 0, 0);
        acc = __builtin_amdgcn_mfma_f32_16x16x32_bf16(xm0, beh0, acc, 0, 0, 0);
        acc = __builtin_amdgcn_mfma_f32_16x16x32_bf16(xm1, beh1, acc, 0, 0, 0);

        // C layout: col = lane&15 (== this code), row = lq*4 + q
#pragma unroll
        for (int q = 0; q < 4; ++q) {
            float s = fmaf(-2.0f, acc[q], eek);
            float old1 = b1[q];
            bool better = s < old1;                   // strict <, ascending t
            b2[q] = fminf(b2[q], better ? old1 : s);
            b1[q] = better ? s : old1;
            i1[q] = better ? code : i1[q];
        }
    }

    // cross-lane argmin over the 16 code-lanes (lex (score, idx)), keep top-2 value
#pragma unroll
    for (int m = 1; m <= 8; m <<= 1) {
#pragma unroll
        for (int q = 0; q < 4; ++q) {
            float c1 = __shfl_xor(b1[q], m, 64);
            float c2 = __shfl_xor(b2[q], m, 64);
            int ci = __shfl_xor(i1[q], m, 64);
            if (c1 < b1[q] || (c1 == b1[q] && ci < i1[q])) {
                b2[q] = fminf(b1[q], c2);
                b1[q] = c1;
                i1[q] = ci;
            } else {
                b2[q] = fminf(b2[q], c1);
            }
        }
    }

    if (lrow == 0) {
#pragma unroll
        for (int q = 0; q < 4; ++q) {
            int r = rowbase + lq * 4 + q;
            idxout[r] = i1[q];
            if (b2[q] - b1[q] < TMARGIN) {           // uncertain -> exact refine
                unsigned pos = atomicAdd(qcount, 1u);
                qrows[pos] = r;
            }
        }
    }
}

// Kernel C: exact re-argmin for queued rows (verified fp32 score path)
__global__ __launch_bounds__(BLK) void vq_refine(
    const float* __restrict__ x, const float* __restrict__ emb,
    const float* __restrict__ ee, const unsigned* __restrict__ qc,
    const int* __restrict__ qrows, int* __restrict__ idxout) {
    const int nwaves = gridDim.x * (BLK / 64);
    const int wid = blockIdx.x * (BLK / 64) + (threadIdx.x >> 6);
    const int lane = threadIdx.x & 63;
    const unsigned n = *qc;

    for (unsigned qi = wid; qi < n; qi += nwaves) {
        const int r = qrows[qi];
        const float4* xv = (const float4*)(x + (size_t)r * C_DIM);
        float best = FLT_MAX;
        int bi = 0;
        for (int kk = 0; kk < 16; ++kk) {
            int k = lane * 16 + kk;   // contiguous partition -> lex reduce is first-min
            const float4* evv = (const float4*)(emb + (size_t)k * C_DIM);
            float d0 = 0.f, d1 = 0.f, d2 = 0.f, d3 = 0.f;
#pragma unroll
            for (int i = 0; i < 16; ++i) {
                float4 xi = xv[i];
                float4 e = evv[i];
                d0 = fmaf(xi.x, e.x, d0);
                d1 = fmaf(xi.y, e.y, d1);
                d2 = fmaf(xi.z, e.z, d2);
                d3 = fmaf(xi.w, e.w, d3);
            }
            float dot = (d0 + d1) + (d2 + d3);
            float s = fmaf(-2.0f, dot, ee[k]);
            if (s < best) { best = s; bi = k; }      // ascending k, strict <
        }
#pragma unroll
        for (int m = 1; m <= 32; m <<= 1) {
            float ob = __shfl_xor(best, m, 64);
            int oi = __shfl_xor(bi, m, 64);
            if (ob < best || (ob == best && oi < bi)) { best = ob; bi = oi; }
        }
        if (lane == 0) idxout[r] = bi;
    }
}

// Kernel D: indices out; histogram; quantized_st + loss partial (verified)
__global__ __launch_bounds__(BLK) void vq_combine(
    const float* __restrict__ x, const float* __restrict__ emb,
    const int* __restrict__ idxin, unsigned* __restrict__ hist,
    float* __restrict__ lossp, float* __restrict__ out) {
    __shared__ int sIdx[BLK];
    __shared__ unsigned sHist[K_CODES];
    __shared__ float sRed[BLK / 64];

    const int t = threadIdx.x;
    const int base = blockIdx.x * BLK;

    for (int i = t; i < K_CODES; i += BLK) sHist[i] = 0u;

    const int row = base + t;
    const int bidx = idxin[row];
    sIdx[t] = bidx;
    out[OUT_IDX + row] = (float)bidx;
    __syncthreads();
    atomicAdd(&sHist[bidx], 1u);
    __syncthreads();
    for (int i = t; i < K_CODES; i += BLK) {
        unsigned c = sHist[i];
        if (c) atomicAdd(&hist[i], c);
    }

    float lsum = 0.f;
    const int rl0 = t >> 6;
    const int col = t & 63;
    for (int it = 0; it < BLK / 4; ++it) {
        const int rl = it * 4 + rl0;
        const int r = base + rl;
        const int bi = sIdx[rl];
        float xv = x[(size_t)r * C_DIM + col];
        float qv = emb[(size_t)bi * C_DIM + col];
        float d = qv - xv;
        out[OUT_Q + (size_t)r * C_DIM + col] = xv + d;  // straight-through
        lsum = fmaf(d, d, lsum);
    }

#pragma unroll
    for (int o = 32; o > 0; o >>= 1) lsum += __shfl_down(lsum, o, 64);
    if ((t & 63) == 0) sRed[t >> 6] = lsum;
    __syncthreads();
    if (t == 0) lossp[blockIdx.x] = (sRed[0] + sRed[1]) + (sRed[2] + sRed[3]);
}

// Kernel E: avg_probs, perplexity, loss finalization
__global__ void vq_final(const unsigned* __restrict__ hist,
                         const float* __restrict__ lossp,
                         float* __restrict__ out) {
    __shared__ float sP[K_CODES];
    __shared__ float sL[K_CODES];
    const int t = threadIdx.x;
    float p = (float)hist[t] * (1.0f / (float)N_ROWS);
    out[OUT_AVG + t] = p;
    sP[t] = p * logf(p + 1e-10f);
    sL[t] = (t < N_ROWS / BLK) ? lossp[t] : 0.f;
    __syncthreads();
    for (int o = 512; o > 0; o >>= 1) {
        if (t < o) { sP[t] += sP[t + o]; sL[t] += sL[t + o]; }
        __syncthreads();
    }
    if (t == 0) {
        out[OUT_PPL] = expf(-sP[0]);
        out[OUT_LOSS] = 0.25f * (sL[0] * (1.0f / (float)(N_ROWS * C_DIM)));
    }
}

extern "C" void kernel_launch(void* const* d_in, const int* in_sizes, int n_in,
                              void* d_out, int out_size, void* d_ws, size_t ws_size,
                              hipStream_t stream) {
    const float* x = (const float*)d_in[0];
    const float* emb = (const float*)d_in[1];
    float* out = (float*)d_out;
    float* ws_f = (float*)d_ws;
    unsigned* ws_u = (unsigned*)d_ws;
    int* ws_i = (int*)d_ws;
    unsigned short* bs = (unsigned short*)(ws_u + WS_BS);

    vq_prep<<<K_CODES / BLK, BLK, 0, stream>>>(emb, ws_f + WS_EE, ws_u + WS_HIST,
                                               bs, ws_u + WS_QC);

    vq_mfma<<<N_ROWS / 64, BLK, 0, stream>>>(x, bs, ws_f + WS_EE,
                                             ws_i + WS_IDX, ws_u + WS_QC,
                                             ws_i + WS_QROWS);

    vq_refine<<<64, BLK, 0, stream>>>(x, emb, ws_f + WS_EE, ws_u + WS_QC,
                                      ws_i + WS_QROWS, ws_i + WS_IDX);

    vq_combine<<<N_ROWS / BLK, BLK, 0, stream>>>(x, emb, ws_i + WS_IDX,
                                                 ws_u + WS_HIST,
                                                 ws_f + WS_LOSSP, out);

    vq_final<<<1, K_CODES, 0, stream>>>(ws_u + WS_HIST, ws_f + WS_LOSSP, out);
}

// Round 6
// 163.260 us; speedup vs baseline: 1.3275x; 1.3275x over previous
//
#include <hip/hip_runtime.h>
#include <math.h>
#include <float.h>

#define N_ROWS 65536
#define K_CODES 1024
#define C_DIM 64
#define BLK 256
#define TMARGIN 0.02f

typedef short s16x8 __attribute__((ext_vector_type(8)));
typedef float f32x4 __attribute__((ext_vector_type(4)));

// d_out layout (float32), outputs concatenated in return order:
// [loss(1)][quantized_st(N*C)][perplexity(1)][indices(N)][avg_probs(K)]
#define OUT_LOSS 0
#define OUT_Q 1
#define OUT_PPL (1 + N_ROWS * C_DIM)     // 4194305
#define OUT_IDX (OUT_PPL + 1)            // 4194306
#define OUT_AVG (OUT_IDX + N_ROWS)       // 4259842

// d_ws layout (4-byte units)
#define WS_HIST 0                        // uint[1024]
#define WS_EE 1024                       // float[1024]
#define WS_LOSSP 2048                    // float[256]
#define WS_QC 2304                       // uint[1] refine-queue count
#define WS_IDX 4096                      // int[N_ROWS] final indices
#define WS_QROWS (WS_IDX + N_ROWS)       // int[N_ROWS] refine queue
#define WS_BS (WS_QROWS + N_ROWS)        // ushort[K_CODES*128 + 2048 pad]

__device__ __forceinline__ unsigned short bf16_rne(float f) {
    unsigned u = __float_as_uint(f);
    return (unsigned short)((u + 0x7FFFu + ((u >> 16) & 1u)) >> 16);
}
__device__ __forceinline__ float bf16_val(unsigned short h) {
    return __uint_as_float(((unsigned)h) << 16);
}

// Kernel A: zero hist, reset queue, ||e||^2 (verified order), split codebook
__global__ void vq_prep(const float* __restrict__ emb, float* __restrict__ ee,
                        unsigned* __restrict__ hist,
                        unsigned short* __restrict__ bs,
                        unsigned* __restrict__ qc) {
    int k = blockIdx.x * BLK + threadIdx.x;
    if (k == 0) *qc = 0u;
    if (k < K_CODES) {
        hist[k] = 0u;
        const float* ev = emb + (size_t)k * C_DIM;
        float s0 = 0.f, s1 = 0.f, s2 = 0.f, s3 = 0.f;
#pragma unroll
        for (int i = 0; i < 16; ++i) {
            float a = ev[4 * i + 0], b = ev[4 * i + 1];
            float c = ev[4 * i + 2], d = ev[4 * i + 3];
            s0 = fmaf(a, a, s0);
            s1 = fmaf(b, b, s1);
            s2 = fmaf(c, c, s2);
            s3 = fmaf(d, d, s3);
        }
        ee[k] = (s0 + s1) + (s2 + s3);
        // split e = eh + em (bf16 RNE twice); layout [code][eh 0..63 | em 0..63]
#pragma unroll 8
        for (int c = 0; c < C_DIM; ++c) {
            float e = ev[c];
            unsigned short h = bf16_rne(e);
            float m = e - bf16_val(h);
            bs[(size_t)k * 128 + c] = h;
            bs[(size_t)k * 128 + 64 + c] = bf16_rne(m);
        }
    }
}

#define LOADB(dst0, dst1, dst2, dst3, p)                    \
    do {                                                    \
        dst0 = *(const s16x8*)(p);                          \
        dst1 = *(const s16x8*)((p) + 32);                   \
        dst2 = *(const s16x8*)((p) + 64);                   \
        dst3 = *(const s16x8*)((p) + 96);                   \
    } while (0)

// Kernel B: MFMA distances, 32 rows/wave (two 16-row sets share each B
// fragment -> half the L2 traffic), 4 independent 3-MFMA chains, 1-deep
// B prefetch. Top-2 + margin -> refine queue (exactness guarantee).
__global__ __launch_bounds__(BLK, 2) void vq_mfma(
    const float* __restrict__ x, const unsigned short* __restrict__ bs,
    const float* __restrict__ ee, int* __restrict__ idxout,
    unsigned* __restrict__ qcount, int* __restrict__ qrows) {
    const int wave = threadIdx.x >> 6;
    const int lane = threadIdx.x & 63;
    const int lrow = lane & 15;          // A-row / C-col lane index
    const int lq = lane >> 4;            // k-quarter / C row-group
    const int rowbase = blockIdx.x * 128 + wave * 32;

    // ---- A fragments for two row-sets (P: rows 0..15, Q: rows 16..31) ----
    s16x8 ph0, ph1, pm0, pm1, qh0, qh1, qm0, qm1;
    {
        const float* xp = x + (size_t)(rowbase + lrow) * C_DIM + lq * 8;
        const float* xq = xp + 16 * C_DIM;
#pragma unroll
        for (int j = 0; j < 8; ++j) {
            float a0 = xp[j], a1 = xp[32 + j];
            float b0 = xq[j], b1v = xq[32 + j];
            unsigned short h;
            h = bf16_rne(a0); ph0[j] = (short)h; pm0[j] = (short)bf16_rne(a0 - bf16_val(h));
            h = bf16_rne(a1); ph1[j] = (short)h; pm1[j] = (short)bf16_rne(a1 - bf16_val(h));
            h = bf16_rne(b0); qh0[j] = (short)h; qm0[j] = (short)bf16_rne(b0 - bf16_val(h));
            h = bf16_rne(b1v); qh1[j] = (short)h; qm1[j] = (short)bf16_rne(b1v - bf16_val(h));
        }
    }

    float b1[8], b2[8];
    int i1[8];
#pragma unroll
    for (int q = 0; q < 8; ++q) { b1[q] = FLT_MAX; b2[q] = FLT_MAX; i1[q] = 0; }

    const unsigned short* bp = bs + (size_t)lrow * 128 + lq * 8;
    s16x8 c0, c1, c2, c3, n0, n1, n2, n3;
    LOADB(c0, c1, c2, c3, bp);

    for (int t = 0; t < K_CODES / 16; ++t) {
        // prefetch next tile (last iter reads the pad region; discarded)
        LOADB(n0, n1, n2, n3, bp + 2048);
        float eek = ee[t * 16 + lrow];

        // 4 independent chains of 3 MFMAs:
        // x.e = xh.eh + xh.em + xm.eh, split by k-half
        f32x4 z = {0.f, 0.f, 0.f, 0.f};
        f32x4 pa = __builtin_amdgcn_mfma_f32_16x16x32_bf16(ph0, c0, z, 0, 0, 0);
        f32x4 pb = __builtin_amdgcn_mfma_f32_16x16x32_bf16(ph1, c1, z, 0, 0, 0);
        f32x4 qa = __builtin_amdgcn_mfma_f32_16x16x32_bf16(qh0, c0, z, 0, 0, 0);
        f32x4 qb = __builtin_amdgcn_mfma_f32_16x16x32_bf16(qh1, c1, z, 0, 0, 0);
        pa = __builtin_amdgcn_mfma_f32_16x16x32_bf16(ph0, c2, pa, 0, 0, 0);
        pb = __builtin_amdgcn_mfma_f32_16x16x32_bf16(ph1, c3, pb, 0, 0, 0);
        qa = __builtin_amdgcn_mfma_f32_16x16x32_bf16(qh0, c2, qa, 0, 0, 0);
        qb = __builtin_amdgcn_mfma_f32_16x16x32_bf16(qh1, c3, qb, 0, 0, 0);
        pa = __builtin_amdgcn_mfma_f32_16x16x32_bf16(pm0, c0, pa, 0, 0, 0);
        pb = __builtin_amdgcn_mfma_f32_16x16x32_bf16(pm1, c1, pb, 0, 0, 0);
        qa = __builtin_amdgcn_mfma_f32_16x16x32_bf16(qm0, c0, qa, 0, 0, 0);
        qb = __builtin_amdgcn_mfma_f32_16x16x32_bf16(qm1, c1, qb, 0, 0, 0);

        const int code = t * 16 + lrow;
#pragma unroll
        for (int q = 0; q < 4; ++q) {
            float sP = fmaf(-2.0f, pa[q] + pb[q], eek);
            float mP = fmaxf(b1[q], sP);
            b2[q] = fminf(b2[q], mP);
            i1[q] = (sP < b1[q]) ? code : i1[q];   // strict <, ascending t
            b1[q] = fminf(b1[q], sP);

            float sQ = fmaf(-2.0f, qa[q] + qb[q], eek);
            float mQ = fmaxf(b1[4 + q], sQ);
            b2[4 + q] = fminf(b2[4 + q], mQ);
            i1[4 + q] = (sQ < b1[4 + q]) ? code : i1[4 + q];
            b1[4 + q] = fminf(b1[4 + q], sQ);
        }

        c0 = n0; c1 = n1; c2 = n2; c3 = n3;
        bp += 2048;
    }

    // cross-lane argmin over the 16 code-lanes (lex (score, idx)), keep top-2
#pragma unroll
    for (int m = 1; m <= 8; m <<= 1) {
#pragma unroll
        for (int q = 0; q < 8; ++q) {
            float ca = __shfl_xor(b1[q], m, 64);
            float cb = __shfl_xor(b2[q], m, 64);
            int ci = __shfl_xor(i1[q], m, 64);
            if (ca < b1[q] || (ca == b1[q] && ci < i1[q])) {
                b2[q] = fminf(b1[q], cb);
                b1[q] = ca;
                i1[q] = ci;
            } else {
                b2[q] = fminf(b2[q], ca);
            }
        }
    }

    if (lrow == 0) {
#pragma unroll
        for (int q = 0; q < 8; ++q) {
            int r = rowbase + (q >> 2) * 16 + lq * 4 + (q & 3);
            idxout[r] = i1[q];
            if (b2[q] - b1[q] < TMARGIN) {           // uncertain -> exact refine
                unsigned pos = atomicAdd(qcount, 1u);
                qrows[pos] = r;
            }
        }
    }
}

// Kernel C: exact re-argmin for queued rows (verified fp32 score path)
__global__ __launch_bounds__(BLK) void vq_refine(
    const float* __restrict__ x, const float* __restrict__ emb,
    const float* __restrict__ ee, const unsigned* __restrict__ qc,
    const int* __restrict__ qrows, int* __restrict__ idxout) {
    const int nwaves = gridDim.x * (BLK / 64);
    const int wid = blockIdx.x * (BLK / 64) + (threadIdx.x >> 6);
    const int lane = threadIdx.x & 63;
    const unsigned n = *qc;

    for (unsigned qi = wid; qi < n; qi += nwaves) {
        const int r = qrows[qi];
        const float4* xv = (const float4*)(x + (size_t)r * C_DIM);
        float best = FLT_MAX;
        int bi = 0;
        for (int kk = 0; kk < 16; ++kk) {
            int k = lane * 16 + kk;   // contiguous partition -> lex reduce is first-min
            const float4* evv = (const float4*)(emb + (size_t)k * C_DIM);
            float d0 = 0.f, d1 = 0.f, d2 = 0.f, d3 = 0.f;
#pragma unroll
            for (int i = 0; i < 16; ++i) {
                float4 xi = xv[i];
                float4 e = evv[i];
                d0 = fmaf(xi.x, e.x, d0);
                d1 = fmaf(xi.y, e.y, d1);
                d2 = fmaf(xi.z, e.z, d2);
                d3 = fmaf(xi.w, e.w, d3);
            }
            float dot = (d0 + d1) + (d2 + d3);
            float s = fmaf(-2.0f, dot, ee[k]);
            if (s < best) { best = s; bi = k; }      // ascending k, strict <
        }
#pragma unroll
        for (int m = 1; m <= 32; m <<= 1) {
            float ob = __shfl_xor(best, m, 64);
            int oi = __shfl_xor(bi, m, 64);
            if (ob < best || (ob == best && oi < bi)) { best = ob; bi = oi; }
        }
        if (lane == 0) idxout[r] = bi;
    }
}

// Kernel D: indices out; histogram; quantized_st + loss partial (verified)
__global__ __launch_bounds__(BLK) void vq_combine(
    const float* __restrict__ x, const float* __restrict__ emb,
    const int* __restrict__ idxin, unsigned* __restrict__ hist,
    float* __restrict__ lossp, float* __restrict__ out) {
    __shared__ int sIdx[BLK];
    __shared__ unsigned sHist[K_CODES];
    __shared__ float sRed[BLK / 64];

    const int t = threadIdx.x;
    const int base = blockIdx.x * BLK;

    for (int i = t; i < K_CODES; i += BLK) sHist[i] = 0u;

    const int row = base + t;
    const int bidx = idxin[row];
    sIdx[t] = bidx;
    out[OUT_IDX + row] = (float)bidx;
    __syncthreads();
    atomicAdd(&sHist[bidx], 1u);
    __syncthreads();
    for (int i = t; i < K_CODES; i += BLK) {
        unsigned c = sHist[i];
        if (c) atomicAdd(&hist[i], c);
    }

    float lsum = 0.f;
    const int rl0 = t >> 6;
    const int col = t & 63;
    for (int it = 0; it < BLK / 4; ++it) {
        const int rl = it * 4 + rl0;
        const int r = base + rl;
        const int bi = sIdx[rl];
        float xv = x[(size_t)r * C_DIM + col];
        float qv = emb[(size_t)bi * C_DIM + col];
        float d = qv - xv;
        out[OUT_Q + (size_t)r * C_DIM + col] = xv + d;  // straight-through
        lsum = fmaf(d, d, lsum);
    }

#pragma unroll
    for (int o = 32; o > 0; o >>= 1) lsum += __shfl_down(lsum, o, 64);
    if ((t & 63) == 0) sRed[t >> 6] = lsum;
    __syncthreads();
    if (t == 0) lossp[blockIdx.x] = (sRed[0] + sRed[1]) + (sRed[2] + sRed[3]);
}

// Kernel E: avg_probs, perplexity, loss finalization
__global__ void vq_final(const unsigned* __restrict__ hist,
                         const float* __restrict__ lossp,
                         float* __restrict__ out) {
    __shared__ float sP[K_CODES];
    __shared__ float sL[K_CODES];
    const int t = threadIdx.x;
    float p = (float)hist[t] * (1.0f / (float)N_ROWS);
    out[OUT_AVG + t] = p;
    sP[t] = p * logf(p + 1e-10f);
    sL[t] = (t < N_ROWS / BLK) ? lossp[t] : 0.f;
    __syncthreads();
    for (int o = 512; o > 0; o >>= 1) {
        if (t < o) { sP[t] += sP[t + o]; sL[t] += sL[t + o]; }
        __syncthreads();
    }
    if (t == 0) {
        out[OUT_PPL] = expf(-sP[0]);
        out[OUT_LOSS] = 0.25f * (sL[0] * (1.0f / (float)(N_ROWS * C_DIM)));
    }
}

extern "C" void kernel_launch(void* const* d_in, const int* in_sizes, int n_in,
                              void* d_out, int out_size, void* d_ws, size_t ws_size,
                              hipStream_t stream) {
    const float* x = (const float*)d_in[0];
    const float* emb = (const float*)d_in[1];
    float* out = (float*)d_out;
    float* ws_f = (float*)d_ws;
    unsigned* ws_u = (unsigned*)d_ws;
    int* ws_i = (int*)d_ws;
    unsigned short* bs = (unsigned short*)(ws_u + WS_BS);

    vq_prep<<<K_CODES / BLK, BLK, 0, stream>>>(emb, ws_f + WS_EE, ws_u + WS_HIST,
                                               bs, ws_u + WS_QC);

    vq_mfma<<<N_ROWS / 128, BLK, 0, stream>>>(x, bs, ws_f + WS_EE,
                                              ws_i + WS_IDX, ws_u + WS_QC,
                                              ws_i + WS_QROWS);

    vq_refine<<<64, BLK, 0, stream>>>(x, emb, ws_f + WS_EE, ws_u + WS_QC,
                                      ws_i + WS_QROWS, ws_i + WS_IDX);

    vq_combine<<<N_ROWS / BLK, BLK, 0, stream>>>(x, emb, ws_i + WS_IDX,
                                                 ws_u + WS_HIST,
                                                 ws_f + WS_LOSSP, out);

    vq_final<<<1, K_CODES, 0, stream>>>(ws_u + WS_HIST, ws_f + WS_LOSSP, out);
}

// Round 7
// 150.313 us; speedup vs baseline: 1.4419x; 1.0861x over previous
//
#include <hip/hip_runtime.h>
#include <math.h>
#include <float.h>

#define N_ROWS 65536
#define K_CODES 1024
#define C_DIM 64
#define BLK 256
#define TMARGIN 0.02f

typedef short s16x8 __attribute__((ext_vector_type(8)));
typedef float f32x4 __attribute__((ext_vector_type(4)));

// d_out layout (float32), outputs concatenated in return order:
// [loss(1)][quantized_st(N*C)][perplexity(1)][indices(N)][avg_probs(K)]
#define OUT_LOSS 0
#define OUT_Q 1
#define OUT_PPL (1 + N_ROWS * C_DIM)     // 4194305
#define OUT_IDX (OUT_PPL + 1)            // 4194306
#define OUT_AVG (OUT_IDX + N_ROWS)       // 4259842

// d_ws layout (4-byte dword offsets). bs and idx ALIAS (bs dead after
// vq_mfma; idx born in vq_merge which runs after).
#define WS_HIST 0            // uint[1024]
#define WS_EE 1024           // float[1024]
#define WS_LOSSP 2048        // float[256]
#define WS_BS_D 4096         // ushort[1024*128 + 2048 pad] = 66560 dwords
#define WS_IDX 4096          // int[N_ROWS] (alias onto bs, safe by lifetime)
#define WS_PB1 70656         // float[2*N_ROWS]
#define WS_PB2 201728        // float[2*N_ROWS]
#define WS_PI1 332800        // int[2*N_ROWS]   (ends 463872 dw = 1.77 MB)

__device__ __forceinline__ unsigned short bf16_rne(float f) {
    unsigned u = __float_as_uint(f);
    return (unsigned short)((u + 0x7FFFu + ((u >> 16) & 1u)) >> 16);
}
__device__ __forceinline__ float bf16_val(unsigned short h) {
    return __uint_as_float(((unsigned)h) << 16);
}

// Kernel A: coalesced elementwise codebook split + hist zero + ee (verified
// 4-class summation order, bit-identical to prior passing kernels).
__global__ __launch_bounds__(BLK) void vq_prep(
    const float* __restrict__ emb, float* __restrict__ ee,
    unsigned* __restrict__ hist, unsigned short* __restrict__ bs) {
    const int gid = blockIdx.x * BLK + threadIdx.x;   // [0, 65536)
    {
        float e = emb[gid];                            // coalesced
        unsigned short h = bf16_rne(e);
        float m = e - bf16_val(h);
        int k = gid >> 6, c = gid & 63;
        bs[(size_t)k * 128 + c] = h;                   // coalesced ushort
        bs[(size_t)k * 128 + 64 + c] = bf16_rne(m);    // coalesced ushort
    }
    if (gid < K_CODES) {
        hist[gid] = 0u;
        const float* ev = emb + (size_t)gid * C_DIM;
        float s0 = 0.f, s1 = 0.f, s2 = 0.f, s3 = 0.f;
#pragma unroll
        for (int i = 0; i < 16; ++i) {
            float a = ev[4 * i + 0], b = ev[4 * i + 1];
            float c = ev[4 * i + 2], d = ev[4 * i + 3];
            s0 = fmaf(a, a, s0);
            s1 = fmaf(b, b, s1);
            s2 = fmaf(c, c, s2);
            s3 = fmaf(d, d, s3);
        }
        ee[gid] = (s0 + s1) + (s2 + s3);
    }
}

#define LOADB(dst0, dst1, dst2, dst3, p)                    \
    do {                                                    \
        dst0 = *(const s16x8*)(p);                          \
        dst1 = *(const s16x8*)((p) + 32);                   \
        dst2 = *(const s16x8*)((p) + 64);                   \
        dst3 = *(const s16x8*)((p) + 96);                   \
    } while (0)

// Kernel B: MFMA distances; 32 rows/wave, K-split x2 (blockIdx.y half) for
// 4 waves/SIMD occupancy; 4 independent 3-MFMA chains; 1-deep B prefetch.
// Per-half (b1,b2,i1) written to deterministic slots (no atomics).
__global__ __launch_bounds__(BLK, 4) void vq_mfma(
    const float* __restrict__ x, const unsigned short* __restrict__ bs,
    const float* __restrict__ ee, float* __restrict__ pb1,
    float* __restrict__ pb2, int* __restrict__ pi1) {
    const int wave = threadIdx.x >> 6;
    const int lane = threadIdx.x & 63;
    const int lrow = lane & 15;          // A-row / C-col lane index
    const int lq = lane >> 4;            // k-quarter / C row-group
    const int rowbase = blockIdx.x * 128 + wave * 32;
    const int half = blockIdx.y;
    const int kbase = half * (K_CODES / 2);

    // ---- A fragments for two row-sets (P: rows 0..15, Q: rows 16..31) ----
    s16x8 ph0, ph1, pm0, pm1, qh0, qh1, qm0, qm1;
    {
        const float* xp = x + (size_t)(rowbase + lrow) * C_DIM + lq * 8;
        const float* xq = xp + 16 * C_DIM;
#pragma unroll
        for (int j = 0; j < 8; ++j) {
            float a0 = xp[j], a1 = xp[32 + j];
            float b0 = xq[j], b1v = xq[32 + j];
            unsigned short h;
            h = bf16_rne(a0); ph0[j] = (short)h; pm0[j] = (short)bf16_rne(a0 - bf16_val(h));
            h = bf16_rne(a1); ph1[j] = (short)h; pm1[j] = (short)bf16_rne(a1 - bf16_val(h));
            h = bf16_rne(b0); qh0[j] = (short)h; qm0[j] = (short)bf16_rne(b0 - bf16_val(h));
            h = bf16_rne(b1v); qh1[j] = (short)h; qm1[j] = (short)bf16_rne(b1v - bf16_val(h));
        }
    }

    float b1[8], b2[8];
    int i1[8];
#pragma unroll
    for (int q = 0; q < 8; ++q) { b1[q] = FLT_MAX; b2[q] = FLT_MAX; i1[q] = 0; }

    const unsigned short* bp = bs + (size_t)(kbase + lrow) * 128 + lq * 8;
    s16x8 c0, c1, c2, c3, n0, n1, n2, n3;
    LOADB(c0, c1, c2, c3, bp);

    for (int t = 0; t < K_CODES / 32; ++t) {          // 32 tiles per half
        // prefetch next tile (last iter reads pad/next-half region; discarded)
        LOADB(n0, n1, n2, n3, bp + 2048);
        float eek = ee[kbase + t * 16 + lrow];

        // x.e = xh.eh + xh.em + xm.eh, split by k-half: 4 chains of 3 MFMAs
        f32x4 z = {0.f, 0.f, 0.f, 0.f};
        f32x4 pa = __builtin_amdgcn_mfma_f32_16x16x32_bf16(ph0, c0, z, 0, 0, 0);
        f32x4 pb = __builtin_amdgcn_mfma_f32_16x16x32_bf16(ph1, c1, z, 0, 0, 0);
        f32x4 qa = __builtin_amdgcn_mfma_f32_16x16x32_bf16(qh0, c0, z, 0, 0, 0);
        f32x4 qb = __builtin_amdgcn_mfma_f32_16x16x32_bf16(qh1, c1, z, 0, 0, 0);
        pa = __builtin_amdgcn_mfma_f32_16x16x32_bf16(ph0, c2, pa, 0, 0, 0);
        pb = __builtin_amdgcn_mfma_f32_16x16x32_bf16(ph1, c3, pb, 0, 0, 0);
        qa = __builtin_amdgcn_mfma_f32_16x16x32_bf16(qh0, c2, qa, 0, 0, 0);
        qb = __builtin_amdgcn_mfma_f32_16x16x32_bf16(qh1, c3, qb, 0, 0, 0);
        pa = __builtin_amdgcn_mfma_f32_16x16x32_bf16(pm0, c0, pa, 0, 0, 0);
        pb = __builtin_amdgcn_mfma_f32_16x16x32_bf16(pm1, c1, pb, 0, 0, 0);
        qa = __builtin_amdgcn_mfma_f32_16x16x32_bf16(qm0, c0, qa, 0, 0, 0);
        qb = __builtin_amdgcn_mfma_f32_16x16x32_bf16(qm1, c1, qb, 0, 0, 0);

        const int code = kbase + t * 16 + lrow;
#pragma unroll
        for (int q = 0; q < 4; ++q) {
            float sP = fmaf(-2.0f, pa[q] + pb[q], eek);
            float mP = fmaxf(b1[q], sP);
            b2[q] = fminf(b2[q], mP);
            i1[q] = (sP < b1[q]) ? code : i1[q];   // strict <, ascending t
            b1[q] = fminf(b1[q], sP);

            float sQ = fmaf(-2.0f, qa[q] + qb[q], eek);
            float mQ = fmaxf(b1[4 + q], sQ);
            b2[4 + q] = fminf(b2[4 + q], mQ);
            i1[4 + q] = (sQ < b1[4 + q]) ? code : i1[4 + q];
            b1[4 + q] = fminf(b1[4 + q], sQ);
        }

        c0 = n0; c1 = n1; c2 = n2; c3 = n3;
        bp += 2048;
    }

    // cross-lane argmin over the 16 code-lanes (lex (score, idx)), keep top-2
#pragma unroll
    for (int m = 1; m <= 8; m <<= 1) {
#pragma unroll
        for (int q = 0; q < 8; ++q) {
            float ca = __shfl_xor(b1[q], m, 64);
            float cb = __shfl_xor(b2[q], m, 64);
            int ci = __shfl_xor(i1[q], m, 64);
            if (ca < b1[q] || (ca == b1[q] && ci < i1[q])) {
                b2[q] = fminf(b1[q], cb);
                b1[q] = ca;
                i1[q] = ci;
            } else {
                b2[q] = fminf(b2[q], ca);
            }
        }
    }

    if (lrow == 0) {
#pragma unroll
        for (int q = 0; q < 8; ++q) {
            int r = rowbase + (q >> 2) * 16 + lq * 4 + (q & 3);
            pb1[half * N_ROWS + r] = b1[q];
            pb2[half * N_ROWS + r] = b2[q];
            pi1[half * N_ROWS + r] = i1[q];
        }
    }
}

// Kernel C: merge halves -> final idx; inline wave-cooperative exact refine
// (fp32 verified score path) for rows whose top-2 margin < TMARGIN.
__global__ __launch_bounds__(BLK) void vq_merge(
    const float* __restrict__ x, const float* __restrict__ emb,
    const float* __restrict__ ee, const float* __restrict__ pb1,
    const float* __restrict__ pb2, const int* __restrict__ pi1,
    int* __restrict__ idxout) {
    const int t = threadIdx.x;
    const int lane = t & 63;
    const int r = blockIdx.x * BLK + t;
    const int wrbase = blockIdx.x * BLK + (t & ~63);

    float a1 = pb1[r], a2 = pb2[r];
    int ai = pi1[r];
    float c1 = pb1[N_ROWS + r], c2 = pb2[N_ROWS + r];
    int ci = pi1[N_ROWS + r];
    // tie -> half 0 (lower code index) wins: strict <
    bool bw = c1 < a1;
    float s1 = bw ? c1 : a1;
    int idx = bw ? ci : ai;
    float s2 = bw ? fminf(c2, a1) : fminf(a2, c1);
    bool flag = (s2 - s1) < TMARGIN;
    if (!flag) idxout[r] = idx;   // flagged rows written only by refine below

    unsigned long long msk = __ballot(flag);
    while (msk) {
        int src = __ffsll((unsigned long long)msk) - 1;
        msk &= (msk - 1);
        const int rr = wrbase + src;
        const float4* xv = (const float4*)(x + (size_t)rr * C_DIM);
        float best = FLT_MAX;
        int bi = 0;
        for (int kk = 0; kk < 16; ++kk) {
            int k = lane * 16 + kk;  // contiguous per-lane -> lex reduce = first-min
            const float4* evv = (const float4*)(emb + (size_t)k * C_DIM);
            float d0 = 0.f, d1 = 0.f, d2 = 0.f, d3 = 0.f;
#pragma unroll
            for (int i = 0; i < 16; ++i) {
                float4 xi = xv[i];
                float4 e = evv[i];
                d0 = fmaf(xi.x, e.x, d0);
                d1 = fmaf(xi.y, e.y, d1);
                d2 = fmaf(xi.z, e.z, d2);
                d3 = fmaf(xi.w, e.w, d3);
            }
            float dot = (d0 + d1) + (d2 + d3);
            float s = fmaf(-2.0f, dot, ee[k]);
            if (s < best) { best = s; bi = k; }      // ascending k, strict <
        }
#pragma unroll
        for (int m = 1; m <= 32; m <<= 1) {
            float ob = __shfl_xor(best, m, 64);
            int oi = __shfl_xor(bi, m, 64);
            if (ob < best || (ob == best && oi < bi)) { best = ob; bi = oi; }
        }
        if (lane == 0) idxout[rr] = bi;
    }
}

// Kernel D: indices out; histogram; quantized_st + loss partial (verified)
__global__ __launch_bounds__(BLK) void vq_combine(
    const float* __restrict__ x, const float* __restrict__ emb,
    const int* __restrict__ idxin, unsigned* __restrict__ hist,
    float* __restrict__ lossp, float* __restrict__ out) {
    __shared__ int sIdx[BLK];
    __shared__ unsigned sHist[K_CODES];
    __shared__ float sRed[BLK / 64];

    const int t = threadIdx.x;
    const int base = blockIdx.x * BLK;

    for (int i = t; i < K_CODES; i += BLK) sHist[i] = 0u;

    const int row = base + t;
    const int bidx = idxin[row];
    sIdx[t] = bidx;
    out[OUT_IDX + row] = (float)bidx;
    __syncthreads();
    atomicAdd(&sHist[bidx], 1u);
    __syncthreads();
    for (int i = t; i < K_CODES; i += BLK) {
        unsigned c = sHist[i];
        if (c) atomicAdd(&hist[i], c);
    }

    float lsum = 0.f;
    const int rl0 = t >> 6;
    const int col = t & 63;
    for (int it = 0; it < BLK / 4; ++it) {
        const int rl = it * 4 + rl0;
        const int r = base + rl;
        const int bi = sIdx[rl];
        float xv = x[(size_t)r * C_DIM + col];
        float qv = emb[(size_t)bi * C_DIM + col];
        float d = qv - xv;
        out[OUT_Q + (size_t)r * C_DIM + col] = xv + d;  // straight-through
        lsum = fmaf(d, d, lsum);
    }

#pragma unroll
    for (int o = 32; o > 0; o >>= 1) lsum += __shfl_down(lsum, o, 64);
    if ((t & 63) == 0) sRed[t >> 6] = lsum;
    __syncthreads();
    if (t == 0) lossp[blockIdx.x] = (sRed[0] + sRed[1]) + (sRed[2] + sRed[3]);
}

// Kernel E: avg_probs, perplexity, loss finalization
__global__ void vq_final(const unsigned* __restrict__ hist,
                         const float* __restrict__ lossp,
                         float* __restrict__ out) {
    __shared__ float sP[K_CODES];
    __shared__ float sL[K_CODES];
    const int t = threadIdx.x;
    float p = (float)hist[t] * (1.0f / (float)N_ROWS);
    out[OUT_AVG + t] = p;
    sP[t] = p * logf(p + 1e-10f);
    sL[t] = (t < N_ROWS / BLK) ? lossp[t] : 0.f;
    __syncthreads();
    for (int o = 512; o > 0; o >>= 1) {
        if (t < o) { sP[t] += sP[t + o]; sL[t] += sL[t + o]; }
        __syncthreads();
    }
    if (t == 0) {
        out[OUT_PPL] = expf(-sP[0]);
        out[OUT_LOSS] = 0.25f * (sL[0] * (1.0f / (float)(N_ROWS * C_DIM)));
    }
}

extern "C" void kernel_launch(void* const* d_in, const int* in_sizes, int n_in,
                              void* d_out, int out_size, void* d_ws, size_t ws_size,
                              hipStream_t stream) {
    const float* x = (const float*)d_in[0];
    const float* emb = (const float*)d_in[1];
    float* out = (float*)d_out;
    float* ws_f = (float*)d_ws;
    unsigned* ws_u = (unsigned*)d_ws;
    int* ws_i = (int*)d_ws;
    unsigned short* bs = (unsigned short*)(ws_u + WS_BS_D);

    vq_prep<<<(N_ROWS / BLK), BLK, 0, stream>>>(emb, ws_f + WS_EE,
                                                ws_u + WS_HIST, bs);

    dim3 gM(N_ROWS / 128, 2);
    vq_mfma<<<gM, BLK, 0, stream>>>(x, bs, ws_f + WS_EE, ws_f + WS_PB1,
                                    ws_f + WS_PB2, ws_i + WS_PI1);

    vq_merge<<<N_ROWS / BLK, BLK, 0, stream>>>(x, emb, ws_f + WS_EE,
                                               ws_f + WS_PB1, ws_f + WS_PB2,
                                               ws_i + WS_PI1, ws_i + WS_IDX);

    vq_combine<<<N_ROWS / BLK, BLK, 0, stream>>>(x, emb, ws_i + WS_IDX,
                                                 ws_u + WS_HIST,
                                                 ws_f + WS_LOSSP, out);

    vq_final<<<1, K_CODES, 0, stream>>>(ws_u + WS_HIST, ws_f + WS_LOSSP, out);
}

// Round 8
// 119.510 us; speedup vs baseline: 1.8135x; 1.2577x over previous
//
#include <hip/hip_runtime.h>
#include <math.h>
#include <float.h>

#define N_ROWS 65536
#define K_CODES 1024
#define C_DIM 64
#define BLK 256
#define TMARGIN 0.02f

typedef short s16x8 __attribute__((ext_vector_type(8)));
typedef float f32x4 __attribute__((ext_vector_type(4)));

// d_out layout (float32), outputs concatenated in return order:
// [loss(1)][quantized_st(N*C)][perplexity(1)][indices(N)][avg_probs(K)]
#define OUT_LOSS 0
#define OUT_Q 1
#define OUT_PPL (1 + N_ROWS * C_DIM)     // 4194305
#define OUT_IDX (OUT_PPL + 1)            // 4194306
#define OUT_AVG (OUT_IDX + N_ROWS)       // 4259842

// d_ws layout (4-byte dword offsets). IDX aliases BS (bs dead after vq_mfma;
// idx born in vq_merge which runs after) — alias proven safe in R7.
#define WS_HIST 0                        // uint[1024]
#define WS_EE 1024                       // float[1024]
#define WS_LOSSP 2048                    // float[256]
#define WS_QC 2304                       // uint[1] refine-queue count
#define WS_QROWS 2560                    // int[N_ROWS]
#define WS_BS_D 68096                    // ushort[1024*128 + 4096 pad] = 67584 dw
#define WS_IDX 68096                     // int[N_ROWS] (alias onto bs)
#define WS_PB1 135680                    // float[2*N_ROWS]
#define WS_PB2 266752                    // float[2*N_ROWS]
#define WS_PI1 397824                    // ushort[2*N_ROWS] (ends 463360 dw = 1.85 MB)

__device__ __forceinline__ unsigned short bf16_rne(float f) {
    unsigned u = __float_as_uint(f);
    return (unsigned short)((u + 0x7FFFu + ((u >> 16) & 1u)) >> 16);
}
__device__ __forceinline__ float bf16_val(unsigned short h) {
    return __uint_as_float(((unsigned)h) << 16);
}

// Kernel A: coalesced codebook split + hist zero + queue reset + ee (verified
// 4-class summation order).
__global__ __launch_bounds__(BLK) void vq_prep(
    const float* __restrict__ emb, float* __restrict__ ee,
    unsigned* __restrict__ hist, unsigned short* __restrict__ bs,
    unsigned* __restrict__ qc) {
    const int gid = blockIdx.x * BLK + threadIdx.x;   // [0, 65536)
    if (gid == 0) *qc = 0u;
    {
        float e = emb[gid];                            // coalesced
        unsigned short h = bf16_rne(e);
        float m = e - bf16_val(h);
        int k = gid >> 6, c = gid & 63;
        bs[(size_t)k * 128 + c] = h;                   // coalesced ushort
        bs[(size_t)k * 128 + 64 + c] = bf16_rne(m);    // coalesced ushort
    }
    if (gid < K_CODES) {
        hist[gid] = 0u;
        const float* ev = emb + (size_t)gid * C_DIM;
        float s0 = 0.f, s1 = 0.f, s2 = 0.f, s3 = 0.f;
#pragma unroll
        for (int i = 0; i < 16; ++i) {
            float a = ev[4 * i + 0], b = ev[4 * i + 1];
            float c = ev[4 * i + 2], d = ev[4 * i + 3];
            s0 = fmaf(a, a, s0);
            s1 = fmaf(b, b, s1);
            s2 = fmaf(c, c, s2);
            s3 = fmaf(d, d, s3);
        }
        ee[gid] = (s0 + s1) + (s2 + s3);
    }
}

#define LOADB(dst0, dst1, dst2, dst3, p)                    \
    do {                                                    \
        dst0 = *(const s16x8*)(p);                          \
        dst1 = *(const s16x8*)((p) + 32);                   \
        dst2 = *(const s16x8*)((p) + 64);                   \
        dst3 = *(const s16x8*)((p) + 96);                   \
    } while (0)

// Kernel B: MFMA distances; 32 rows/wave; K-split x2; 4 independent 3-MFMA
// chains; 1-deep prefetch of BOTH the B tile AND eek (no same-iteration
// VMEM dependency left in the loop).
__global__ __launch_bounds__(BLK, 4) void vq_mfma(
    const float* __restrict__ x, const unsigned short* __restrict__ bs,
    const float* __restrict__ ee, float* __restrict__ pb1,
    float* __restrict__ pb2, unsigned short* __restrict__ pi1) {
    const int wave = threadIdx.x >> 6;
    const int lane = threadIdx.x & 63;
    const int lrow = lane & 15;          // A-row / C-col lane index
    const int lq = lane >> 4;            // k-quarter / C row-group
    const int rowbase = blockIdx.x * 128 + wave * 32;
    const int half = blockIdx.y;
    const int kbase = half * (K_CODES / 2);

    // ---- A fragments for two row-sets (P: rows 0..15, Q: rows 16..31) ----
    s16x8 ph0, ph1, pm0, pm1, qh0, qh1, qm0, qm1;
    {
        const float* xp = x + (size_t)(rowbase + lrow) * C_DIM + lq * 8;
        const float* xq = xp + 16 * C_DIM;
#pragma unroll
        for (int j = 0; j < 8; ++j) {
            float a0 = xp[j], a1 = xp[32 + j];
            float b0 = xq[j], b1v = xq[32 + j];
            unsigned short h;
            h = bf16_rne(a0); ph0[j] = (short)h; pm0[j] = (short)bf16_rne(a0 - bf16_val(h));
            h = bf16_rne(a1); ph1[j] = (short)h; pm1[j] = (short)bf16_rne(a1 - bf16_val(h));
            h = bf16_rne(b0); qh0[j] = (short)h; qm0[j] = (short)bf16_rne(b0 - bf16_val(h));
            h = bf16_rne(b1v); qh1[j] = (short)h; qm1[j] = (short)bf16_rne(b1v - bf16_val(h));
        }
    }

    float b1[8], b2[8];
    int i1[8];
#pragma unroll
    for (int q = 0; q < 8; ++q) { b1[q] = FLT_MAX; b2[q] = FLT_MAX; i1[q] = 0; }

    const unsigned short* bp = bs + (size_t)(kbase + lrow) * 128 + lq * 8;
    s16x8 c0, c1, c2, c3, n0, n1, n2, n3;
    LOADB(c0, c1, c2, c3, bp);
    float eek = ee[kbase + lrow];

    for (int t = 0; t < K_CODES / 32; ++t) {          // 32 tiles per half
        // prefetch next tile's B AND eek (last iter reads pad/adjacent ws
        // region; values discarded)
        LOADB(n0, n1, n2, n3, bp + 2048);
        float eekn = ee[kbase + (t + 1) * 16 + lrow];

        // x.e = xh.eh + xh.em + xm.eh, split by k-half: 4 chains of 3 MFMAs
        f32x4 z = {0.f, 0.f, 0.f, 0.f};
        f32x4 pa = __builtin_amdgcn_mfma_f32_16x16x32_bf16(ph0, c0, z, 0, 0, 0);
        f32x4 pb = __builtin_amdgcn_mfma_f32_16x16x32_bf16(ph1, c1, z, 0, 0, 0);
        f32x4 qa = __builtin_amdgcn_mfma_f32_16x16x32_bf16(qh0, c0, z, 0, 0, 0);
        f32x4 qb = __builtin_amdgcn_mfma_f32_16x16x32_bf16(qh1, c1, z, 0, 0, 0);
        pa = __builtin_amdgcn_mfma_f32_16x16x32_bf16(ph0, c2, pa, 0, 0, 0);
        pb = __builtin_amdgcn_mfma_f32_16x16x32_bf16(ph1, c3, pb, 0, 0, 0);
        qa = __builtin_amdgcn_mfma_f32_16x16x32_bf16(qh0, c2, qa, 0, 0, 0);
        qb = __builtin_amdgcn_mfma_f32_16x16x32_bf16(qh1, c3, qb, 0, 0, 0);
        pa = __builtin_amdgcn_mfma_f32_16x16x32_bf16(pm0, c0, pa, 0, 0, 0);
        pb = __builtin_amdgcn_mfma_f32_16x16x32_bf16(pm1, c1, pb, 0, 0, 0);
        qa = __builtin_amdgcn_mfma_f32_16x16x32_bf16(qm0, c0, qa, 0, 0, 0);
        qb = __builtin_amdgcn_mfma_f32_16x16x32_bf16(qm1, c1, qb, 0, 0, 0);

        const int code = kbase + t * 16 + lrow;
#pragma unroll
        for (int q = 0; q < 4; ++q) {
            float sP = fmaf(-2.0f, pa[q] + pb[q], eek);
            float mP = fmaxf(b1[q], sP);
            b2[q] = fminf(b2[q], mP);
            i1[q] = (sP < b1[q]) ? code : i1[q];   // strict <, ascending t
            b1[q] = fminf(b1[q], sP);

            float sQ = fmaf(-2.0f, qa[q] + qb[q], eek);
            float mQ = fmaxf(b1[4 + q], sQ);
            b2[4 + q] = fminf(b2[4 + q], mQ);
            i1[4 + q] = (sQ < b1[4 + q]) ? code : i1[4 + q];
            b1[4 + q] = fminf(b1[4 + q], sQ);
        }

        c0 = n0; c1 = n1; c2 = n2; c3 = n3;
        eek = eekn;
        bp += 2048;
    }

    // cross-lane argmin over the 16 code-lanes (lex (score, idx)), keep top-2
#pragma unroll
    for (int m = 1; m <= 8; m <<= 1) {
#pragma unroll
        for (int q = 0; q < 8; ++q) {
            float ca = __shfl_xor(b1[q], m, 64);
            float cb = __shfl_xor(b2[q], m, 64);
            int ci = __shfl_xor(i1[q], m, 64);
            if (ca < b1[q] || (ca == b1[q] && ci < i1[q])) {
                b2[q] = fminf(b1[q], cb);
                b1[q] = ca;
                i1[q] = ci;
            } else {
                b2[q] = fminf(b2[q], ca);
            }
        }
    }

    if (lrow == 0) {
#pragma unroll
        for (int q = 0; q < 8; ++q) {
            int r = rowbase + (q >> 2) * 16 + lq * 4 + (q & 3);
            pb1[half * N_ROWS + r] = b1[q];
            pb2[half * N_ROWS + r] = b2[q];
            pi1[half * N_ROWS + r] = (unsigned short)i1[q];
        }
    }
}

// Kernel C: elementwise merge of the two K-halves; flagged rows -> queue.
__global__ __launch_bounds__(BLK) void vq_merge(
    const float* __restrict__ pb1, const float* __restrict__ pb2,
    const unsigned short* __restrict__ pi1, int* __restrict__ idxout,
    unsigned* __restrict__ qc, int* __restrict__ qrows) {
    const int r = blockIdx.x * BLK + threadIdx.x;
    float a1 = pb1[r], a2 = pb2[r];
    int ai = pi1[r];
    float c1 = pb1[N_ROWS + r], c2 = pb2[N_ROWS + r];
    int ci = pi1[N_ROWS + r];
    // tie -> half 0 (lower code index) wins: strict <
    bool bw = c1 < a1;
    float s1 = bw ? c1 : a1;
    int idx = bw ? ci : ai;
    float s2 = bw ? fminf(c2, a1) : fminf(a2, c1);
    idxout[r] = idx;                      // refine overwrites flagged rows
    if (s2 - s1 < TMARGIN) {
        unsigned p = atomicAdd(qc, 1u);
        qrows[p] = r;
    }
}

// Kernel D: exact re-argmin, ONE BLOCK PER FLAGGED ROW (block-strided queue).
// Lane owns 4 consecutive codes; 4 waves cover K; verified fp32 score path.
__global__ __launch_bounds__(BLK) void vq_refine(
    const float* __restrict__ x, const float* __restrict__ emb,
    const float* __restrict__ ee, const unsigned* __restrict__ qc,
    const int* __restrict__ qrows, int* __restrict__ idxout) {
    __shared__ float sB[4];
    __shared__ int sI[4];
    const int w = threadIdx.x >> 6;
    const int lane = threadIdx.x & 63;
    const unsigned n = *qc;

    for (unsigned qi = blockIdx.x; qi < n; qi += gridDim.x) {
        const int r = qrows[qi];
        const float4* xv = (const float4*)(x + (size_t)r * C_DIM);
        float best = FLT_MAX;
        int bi = 0;
#pragma unroll
        for (int j = 0; j < 4; ++j) {
            const int k = w * 256 + lane * 4 + j;   // ascending j -> ascending k
            const float4* evv = (const float4*)(emb + (size_t)k * C_DIM);
            float d0 = 0.f, d1 = 0.f, d2 = 0.f, d3 = 0.f;
#pragma unroll
            for (int i = 0; i < 16; ++i) {
                float4 xi = xv[i];
                float4 e = evv[i];
                d0 = fmaf(xi.x, e.x, d0);
                d1 = fmaf(xi.y, e.y, d1);
                d2 = fmaf(xi.z, e.z, d2);
                d3 = fmaf(xi.w, e.w, d3);
            }
            float dot = (d0 + d1) + (d2 + d3);
            float s = fmaf(-2.0f, dot, ee[k]);
            if (s < best) { best = s; bi = k; }      // strict <: first-min
        }
#pragma unroll
        for (int m = 1; m <= 32; m <<= 1) {
            float ob = __shfl_xor(best, m, 64);
            int oi = __shfl_xor(bi, m, 64);
            if (ob < best || (ob == best && oi < bi)) { best = ob; bi = oi; }
        }
        if (lane == 0) { sB[w] = best; sI[w] = bi; }
        __syncthreads();
        if (threadIdx.x == 0) {
            float b = sB[0];
            int i = sI[0];
#pragma unroll
            for (int w2 = 1; w2 < 4; ++w2) {
                if (sB[w2] < b || (sB[w2] == b && sI[w2] < i)) { b = sB[w2]; i = sI[w2]; }
            }
            idxout[r] = i;
        }
        __syncthreads();
    }
}

// Kernel E: indices out; histogram; quantized_st + loss partial (verified)
__global__ __launch_bounds__(BLK) void vq_combine(
    const float* __restrict__ x, const float* __restrict__ emb,
    const int* __restrict__ idxin, unsigned* __restrict__ hist,
    float* __restrict__ lossp, float* __restrict__ out) {
    __shared__ int sIdx[BLK];
    __shared__ unsigned sHist[K_CODES];
    __shared__ float sRed[BLK / 64];

    const int t = threadIdx.x;
    const int base = blockIdx.x * BLK;

    for (int i = t; i < K_CODES; i += BLK) sHist[i] = 0u;

    const int row = base + t;
    const int bidx = idxin[row];
    sIdx[t] = bidx;
    out[OUT_IDX + row] = (float)bidx;
    __syncthreads();
    atomicAdd(&sHist[bidx], 1u);
    __syncthreads();
    for (int i = t; i < K_CODES; i += BLK) {
        unsigned c = sHist[i];
        if (c) atomicAdd(&hist[i], c);
    }

    float lsum = 0.f;
    const int rl0 = t >> 6;
    const int col = t & 63;
    for (int it = 0; it < BLK / 4; ++it) {
        const int rl = it * 4 + rl0;
        const int r = base + rl;
        const int bi = sIdx[rl];
        float xv = x[(size_t)r * C_DIM + col];
        float qv = emb[(size_t)bi * C_DIM + col];
        float d = qv - xv;
        out[OUT_Q + (size_t)r * C_DIM + col] = xv + d;  // straight-through
        lsum = fmaf(d, d, lsum);
    }

#pragma unroll
    for (int o = 32; o > 0; o >>= 1) lsum += __shfl_down(lsum, o, 64);
    if ((t & 63) == 0) sRed[t >> 6] = lsum;
    __syncthreads();
    if (t == 0) lossp[blockIdx.x] = (sRed[0] + sRed[1]) + (sRed[2] + sRed[3]);
}

// Kernel F: avg_probs, perplexity, loss finalization
__global__ void vq_final(const unsigned* __restrict__ hist,
                         const float* __restrict__ lossp,
                         float* __restrict__ out) {
    __shared__ float sP[K_CODES];
    __shared__ float sL[K_CODES];
    const int t = threadIdx.x;
    float p = (float)hist[t] * (1.0f / (float)N_ROWS);
    out[OUT_AVG + t] = p;
    sP[t] = p * logf(p + 1e-10f);
    sL[t] = (t < N_ROWS / BLK) ? lossp[t] : 0.f;
    __syncthreads();
    for (int o = 512; o > 0; o >>= 1) {
        if (t < o) { sP[t] += sP[t + o]; sL[t] += sL[t + o]; }
        __syncthreads();
    }
    if (t == 0) {
        out[OUT_PPL] = expf(-sP[0]);
        out[OUT_LOSS] = 0.25f * (sL[0] * (1.0f / (float)(N_ROWS * C_DIM)));
    }
}

extern "C" void kernel_launch(void* const* d_in, const int* in_sizes, int n_in,
                              void* d_out, int out_size, void* d_ws, size_t ws_size,
                              hipStream_t stream) {
    const float* x = (const float*)d_in[0];
    const float* emb = (const float*)d_in[1];
    float* out = (float*)d_out;
    float* ws_f = (float*)d_ws;
    unsigned* ws_u = (unsigned*)d_ws;
    int* ws_i = (int*)d_ws;
    unsigned short* bs = (unsigned short*)(ws_u + WS_BS_D);
    unsigned short* pi1 = (unsigned short*)(ws_u + WS_PI1);

    vq_prep<<<N_ROWS / BLK, BLK, 0, stream>>>(emb, ws_f + WS_EE, ws_u + WS_HIST,
                                              bs, ws_u + WS_QC);

    dim3 gM(N_ROWS / 128, 2);
    vq_mfma<<<gM, BLK, 0, stream>>>(x, bs, ws_f + WS_EE, ws_f + WS_PB1,
                                    ws_f + WS_PB2, pi1);

    vq_merge<<<N_ROWS / BLK, BLK, 0, stream>>>(ws_f + WS_PB1, ws_f + WS_PB2,
                                               pi1, ws_i + WS_IDX,
                                               ws_u + WS_QC, ws_i + WS_QROWS);

    vq_refine<<<1024, BLK, 0, stream>>>(x, emb, ws_f + WS_EE, ws_u + WS_QC,
                                        ws_i + WS_QROWS, ws_i + WS_IDX);

    vq_combine<<<N_ROWS / BLK, BLK, 0, stream>>>(x, emb, ws_i + WS_IDX,
                                                 ws_u + WS_HIST,
                                                 ws_f + WS_LOSSP, out);

    vq_final<<<1, K_CODES, 0, stream>>>(ws_u + WS_HIST, ws_f + WS_LOSSP, out);
}

// Round 9
// 92.870 us; speedup vs baseline: 2.3337x; 1.2868x over previous
//
#include <hip/hip_runtime.h>
#include <math.h>
#include <float.h>

#define N_ROWS 65536
#define K_CODES 1024
#define C_DIM 64
#define BLK 256
#define TMARGIN 0.02f

typedef short s16x8 __attribute__((ext_vector_type(8)));
typedef float f32x4 __attribute__((ext_vector_type(4)));

// d_out layout (float32), outputs concatenated in return order:
// [loss(1)][quantized_st(N*C)][perplexity(1)][indices(N)][avg_probs(K)]
#define OUT_LOSS 0
#define OUT_Q 1
#define OUT_PPL (1 + N_ROWS * C_DIM)     // 4194305
#define OUT_IDX (OUT_PPL + 1)            // 4194306
#define OUT_AVG (OUT_IDX + N_ROWS)       // 4259842

// d_ws layout (4-byte dword offsets). IDX aliases BS (bs dead after vq_mfma;
// idx born in vq_merge which runs after) — alias proven safe in R7/R8.
#define WS_HIST 0                        // uint[1024]
#define WS_EE 1024                       // float[1024]
#define WS_LOSSP 2048                    // float[256]
#define WS_QC 2304                       // uint[1] refine-queue count
#define WS_QROWS 2560                    // int[N_ROWS]
#define WS_BS_D 68096                    // ushort[1024*128] = 65536 dw
#define WS_IDX 68096                     // int[N_ROWS] (alias onto bs)
#define WS_PB1 135680                    // float[2*N_ROWS]
#define WS_PB2 266752                    // float[2*N_ROWS]
#define WS_PI1 397824                    // ushort[2*N_ROWS] (ends 463360 dw = 1.85 MB)

__device__ __forceinline__ unsigned short bf16_rne(float f) {
    unsigned u = __float_as_uint(f);
    return (unsigned short)((u + 0x7FFFu + ((u >> 16) & 1u)) >> 16);
}
__device__ __forceinline__ float bf16_val(unsigned short h) {
    return __uint_as_float(((unsigned)h) << 16);
}

// Kernel A: coalesced codebook split + hist zero + queue reset + ee (verified
// 4-class summation order).
__global__ __launch_bounds__(BLK) void vq_prep(
    const float* __restrict__ emb, float* __restrict__ ee,
    unsigned* __restrict__ hist, unsigned short* __restrict__ bs,
    unsigned* __restrict__ qc) {
    const int gid = blockIdx.x * BLK + threadIdx.x;   // [0, 65536)
    if (gid == 0) *qc = 0u;
    {
        float e = emb[gid];                            // coalesced
        unsigned short h = bf16_rne(e);
        float m = e - bf16_val(h);
        int k = gid >> 6, c = gid & 63;
        bs[(size_t)k * 128 + c] = h;                   // coalesced ushort
        bs[(size_t)k * 128 + 64 + c] = bf16_rne(m);    // coalesced ushort
    }
    if (gid < K_CODES) {
        hist[gid] = 0u;
        const float* ev = emb + (size_t)gid * C_DIM;
        float s0 = 0.f, s1 = 0.f, s2 = 0.f, s3 = 0.f;
#pragma unroll
        for (int i = 0; i < 16; ++i) {
            float a = ev[4 * i + 0], b = ev[4 * i + 1];
            float c = ev[4 * i + 2], d = ev[4 * i + 3];
            s0 = fmaf(a, a, s0);
            s1 = fmaf(b, b, s1);
            s2 = fmaf(c, c, s2);
            s3 = fmaf(d, d, s3);
        }
        ee[gid] = (s0 + s1) + (s2 + s3);
    }
}

// async global->LDS, 16B per lane; LDS dest must be WAVE-UNIFORM base
#define GLD16(gsrc, ldst)                                                     \
    __builtin_amdgcn_global_load_lds(                                         \
        (const __attribute__((address_space(1))) unsigned int*)(gsrc),        \
        (__attribute__((address_space(3))) unsigned int*)(ldst), 16, 0, 0)

// Kernel B: MFMA distances; B tiles staged in LDS once per block (4 waves
// share), double-buffered 2-phase, XOR-swizzled layout (pre-swizzled global
// source + swizzled ds_read, rule #21). ee staged in LDS. Same 12-MFMA
// numerics as the verified R8 kernel -> scores bit-identical.
__global__ __launch_bounds__(BLK, 4) void vq_mfma(
    const float* __restrict__ x, const unsigned short* __restrict__ bs,
    const float* __restrict__ ee, float* __restrict__ pb1,
    float* __restrict__ pb2, unsigned short* __restrict__ pi1) {
    __shared__ __align__(16) unsigned char sB[2][4096];  // 2 x (16 codes x 256B)
    __shared__ float sEE[512];

    const int tid = threadIdx.x;
    const int wave = tid >> 6;
    const int lane = tid & 63;
    const int lrow = lane & 15;          // A-row / C-col lane index
    const int lq = lane >> 4;            // k-quarter / C row-group
    const int rowbase = blockIdx.x * 128 + wave * 32;
    const int half = blockIdx.y;
    const int kbase = half * (K_CODES / 2);

    // stage ee for this K-half (512 floats)
    sEE[tid] = ee[kbase + tid];
    sEE[tid + 256] = ee[kbase + tid + 256];

    // per-thread pre-swizzled global source for B staging:
    // thread tid owns LDS bytes [tid*16, tid*16+16): row=tid>>4, slot z=tid&15;
    // content = B[row][(z ^ (row&7))*16 ...]
    const int srow = tid >> 4;
    const int sz8 = ((tid & 15) ^ (srow & 7)) * 8;       // ushort offset
    const unsigned short* sbase =
        bs + (size_t)(kbase + srow) * 128 + sz8;          // + t*16*128 per tile

    // ---- A fragments for two row-sets (P: rows 0..15, Q: rows 16..31) ----
    s16x8 ph0, ph1, pm0, pm1, qh0, qh1, qm0, qm1;
    {
        const float* xp = x + (size_t)(rowbase + lrow) * C_DIM + lq * 8;
        const float* xq = xp + 16 * C_DIM;
#pragma unroll
        for (int j = 0; j < 8; ++j) {
            float a0 = xp[j], a1 = xp[32 + j];
            float b0 = xq[j], b1v = xq[32 + j];
            unsigned short h;
            h = bf16_rne(a0); ph0[j] = (short)h; pm0[j] = (short)bf16_rne(a0 - bf16_val(h));
            h = bf16_rne(a1); ph1[j] = (short)h; pm1[j] = (short)bf16_rne(a1 - bf16_val(h));
            h = bf16_rne(b0); qh0[j] = (short)h; qm0[j] = (short)bf16_rne(b0 - bf16_val(h));
            h = bf16_rne(b1v); qh1[j] = (short)h; qm1[j] = (short)bf16_rne(b1v - bf16_val(h));
        }
    }

    float b1[8], b2[8];
    int i1[8];
#pragma unroll
    for (int q = 0; q < 8; ++q) { b1[q] = FLT_MAX; b2[q] = FLT_MAX; i1[q] = 0; }

    // swizzled ds_read byte offsets for this lane (within a 4KB tile)
    const int rb = lrow * 256;
    const int swz = (lrow & 7) << 4;
    const int o0 = rb + ((0 + lq * 16) ^ swz);
    const int o1 = rb + ((64 + lq * 16) ^ swz);
    const int o2 = rb + ((128 + lq * 16) ^ swz);
    const int o3 = rb + ((192 + lq * 16) ^ swz);

    // prologue: stage tile 0 into buffer 0
    GLD16(sbase, &sB[0][wave * 1024]);
    __syncthreads();   // drains vmcnt + barrier (compiler full-drain)

    int buf = 0;
    for (int t = 0; t < 32; ++t) {          // 32 tiles of 16 codes per half
        if (t + 1 < 32)                      // stage next tile into other buf
            GLD16(sbase + (size_t)(t + 1) * 16 * 128, &sB[buf ^ 1][wave * 1024]);

        const unsigned char* bb = &sB[buf][0];
        s16x8 c0 = *(const s16x8*)(bb + o0);
        s16x8 c1 = *(const s16x8*)(bb + o1);
        s16x8 c2 = *(const s16x8*)(bb + o2);
        s16x8 c3 = *(const s16x8*)(bb + o3);
        float eek = sEE[t * 16 + lrow];

        // x.e = xh.eh + xh.em + xm.eh, split by k-half: 4 chains of 3 MFMAs
        f32x4 z = {0.f, 0.f, 0.f, 0.f};
        f32x4 pa = __builtin_amdgcn_mfma_f32_16x16x32_bf16(ph0, c0, z, 0, 0, 0);
        f32x4 pb = __builtin_amdgcn_mfma_f32_16x16x32_bf16(ph1, c1, z, 0, 0, 0);
        f32x4 qa = __builtin_amdgcn_mfma_f32_16x16x32_bf16(qh0, c0, z, 0, 0, 0);
        f32x4 qb = __builtin_amdgcn_mfma_f32_16x16x32_bf16(qh1, c1, z, 0, 0, 0);
        pa = __builtin_amdgcn_mfma_f32_16x16x32_bf16(ph0, c2, pa, 0, 0, 0);
        pb = __builtin_amdgcn_mfma_f32_16x16x32_bf16(ph1, c3, pb, 0, 0, 0);
        qa = __builtin_amdgcn_mfma_f32_16x16x32_bf16(qh0, c2, qa, 0, 0, 0);
        qb = __builtin_amdgcn_mfma_f32_16x16x32_bf16(qh1, c3, qb, 0, 0, 0);
        pa = __builtin_amdgcn_mfma_f32_16x16x32_bf16(pm0, c0, pa, 0, 0, 0);
        pb = __builtin_amdgcn_mfma_f32_16x16x32_bf16(pm1, c1, pb, 0, 0, 0);
        qa = __builtin_amdgcn_mfma_f32_16x16x32_bf16(qm0, c0, qa, 0, 0, 0);
        qb = __builtin_amdgcn_mfma_f32_16x16x32_bf16(qm1, c1, qb, 0, 0, 0);

        const int code = kbase + t * 16 + lrow;
#pragma unroll
        for (int q = 0; q < 4; ++q) {
            float sP = fmaf(-2.0f, pa[q] + pb[q], eek);
            float mP = fmaxf(b1[q], sP);
            b2[q] = fminf(b2[q], mP);                 // med3 pattern
            i1[q] = (sP < b1[q]) ? code : i1[q];      // strict <, ascending t
            b1[q] = fminf(b1[q], sP);

            float sQ = fmaf(-2.0f, qa[q] + qb[q], eek);
            float mQ = fmaxf(b1[4 + q], sQ);
            b2[4 + q] = fminf(b2[4 + q], mQ);
            i1[4 + q] = (sQ < b1[4 + q]) ? code : i1[4 + q];
            b1[4 + q] = fminf(b1[4 + q], sQ);
        }

        __syncthreads();   // staged tile t+1 ready; all reads of buf done
        buf ^= 1;
    }

    // cross-lane argmin over the 16 code-lanes (lex (score, idx)), keep top-2
#pragma unroll
    for (int m = 1; m <= 8; m <<= 1) {
#pragma unroll
        for (int q = 0; q < 8; ++q) {
            float ca = __shfl_xor(b1[q], m, 64);
            float cb = __shfl_xor(b2[q], m, 64);
            int ci = __shfl_xor(i1[q], m, 64);
            if (ca < b1[q] || (ca == b1[q] && ci < i1[q])) {
                b2[q] = fminf(b1[q], cb);
                b1[q] = ca;
                i1[q] = ci;
            } else {
                b2[q] = fminf(b2[q], ca);
            }
        }
    }

    if (lrow == 0) {
#pragma unroll
        for (int q = 0; q < 8; ++q) {
            int r = rowbase + (q >> 2) * 16 + lq * 4 + (q & 3);
            pb1[half * N_ROWS + r] = b1[q];
            pb2[half * N_ROWS + r] = b2[q];
            pi1[half * N_ROWS + r] = (unsigned short)i1[q];
        }
    }
}

// Kernel C: elementwise merge of the two K-halves; flagged rows -> queue.
__global__ __launch_bounds__(BLK) void vq_merge(
    const float* __restrict__ pb1, const float* __restrict__ pb2,
    const unsigned short* __restrict__ pi1, int* __restrict__ idxout,
    unsigned* __restrict__ qc, int* __restrict__ qrows) {
    const int r = blockIdx.x * BLK + threadIdx.x;
    float a1 = pb1[r], a2 = pb2[r];
    int ai = pi1[r];
    float c1 = pb1[N_ROWS + r], c2 = pb2[N_ROWS + r];
    int ci = pi1[N_ROWS + r];
    // tie -> half 0 (lower code index) wins: strict <
    bool bw = c1 < a1;
    float s1 = bw ? c1 : a1;
    int idx = bw ? ci : ai;
    float s2 = bw ? fminf(c2, a1) : fminf(a2, c1);
    idxout[r] = idx;                      // refine overwrites flagged rows
    if (s2 - s1 < TMARGIN) {
        unsigned p = atomicAdd(qc, 1u);
        qrows[p] = r;
    }
}

// Kernel D: exact re-argmin, ONE BLOCK PER FLAGGED ROW (block-strided queue).
// Lane owns 4 consecutive codes; 4 waves cover K; verified fp32 score path.
__global__ __launch_bounds__(BLK) void vq_refine(
    const float* __restrict__ x, const float* __restrict__ emb,
    const float* __restrict__ ee, const unsigned* __restrict__ qc,
    const int* __restrict__ qrows, int* __restrict__ idxout) {
    __shared__ float sB[4];
    __shared__ int sI[4];
    const int w = threadIdx.x >> 6;
    const int lane = threadIdx.x & 63;
    const unsigned n = *qc;

    for (unsigned qi = blockIdx.x; qi < n; qi += gridDim.x) {
        const int r = qrows[qi];
        const float4* xv = (const float4*)(x + (size_t)r * C_DIM);
        float best = FLT_MAX;
        int bi = 0;
#pragma unroll
        for (int j = 0; j < 4; ++j) {
            const int k = w * 256 + lane * 4 + j;   // ascending j -> ascending k
            const float4* evv = (const float4*)(emb + (size_t)k * C_DIM);
            float d0 = 0.f, d1 = 0.f, d2 = 0.f, d3 = 0.f;
#pragma unroll
            for (int i = 0; i < 16; ++i) {
                float4 xi = xv[i];
                float4 e = evv[i];
                d0 = fmaf(xi.x, e.x, d0);
                d1 = fmaf(xi.y, e.y, d1);
                d2 = fmaf(xi.z, e.z, d2);
                d3 = fmaf(xi.w, e.w, d3);
            }
            float dot = (d0 + d1) + (d2 + d3);
            float s = fmaf(-2.0f, dot, ee[k]);
            if (s < best) { best = s; bi = k; }      // strict <: first-min
        }
#pragma unroll
        for (int m = 1; m <= 32; m <<= 1) {
            float ob = __shfl_xor(best, m, 64);
            int oi = __shfl_xor(bi, m, 64);
            if (ob < best || (ob == best && oi < bi)) { best = ob; bi = oi; }
        }
        if (lane == 0) { sB[w] = best; sI[w] = bi; }
        __syncthreads();
        if (threadIdx.x == 0) {
            float b = sB[0];
            int i = sI[0];
#pragma unroll
            for (int w2 = 1; w2 < 4; ++w2) {
                if (sB[w2] < b || (sB[w2] == b && sI[w2] < i)) { b = sB[w2]; i = sI[w2]; }
            }
            idxout[r] = i;
        }
        __syncthreads();
    }
}

// Kernel E: indices out; histogram; quantized_st + loss partial (verified)
__global__ __launch_bounds__(BLK) void vq_combine(
    const float* __restrict__ x, const float* __restrict__ emb,
    const int* __restrict__ idxin, unsigned* __restrict__ hist,
    float* __restrict__ lossp, float* __restrict__ out) {
    __shared__ int sIdx[BLK];
    __shared__ unsigned sHist[K_CODES];
    __shared__ float sRed[BLK / 64];

    const int t = threadIdx.x;
    const int base = blockIdx.x * BLK;

    for (int i = t; i < K_CODES; i += BLK) sHist[i] = 0u;

    const int row = base + t;
    const int bidx = idxin[row];
    sIdx[t] = bidx;
    out[OUT_IDX + row] = (float)bidx;
    __syncthreads();
    atomicAdd(&sHist[bidx], 1u);
    __syncthreads();
    for (int i = t; i < K_CODES; i += BLK) {
        unsigned c = sHist[i];
        if (c) atomicAdd(&hist[i], c);
    }

    float lsum = 0.f;
    const int rl0 = t >> 6;
    const int col = t & 63;
    for (int it = 0; it < BLK / 4; ++it) {
        const int rl = it * 4 + rl0;
        const int r = base + rl;
        const int bi = sIdx[rl];
        float xv = x[(size_t)r * C_DIM + col];
        float qv = emb[(size_t)bi * C_DIM + col];
        float d = qv - xv;
        out[OUT_Q + (size_t)r * C_DIM + col] = xv + d;  // straight-through
        lsum = fmaf(d, d, lsum);
    }

#pragma unroll
    for (int o = 32; o > 0; o >>= 1) lsum += __shfl_down(lsum, o, 64);
    if ((t & 63) == 0) sRed[t >> 6] = lsum;
    __syncthreads();
    if (t == 0) lossp[blockIdx.x] = (sRed[0] + sRed[1]) + (sRed[2] + sRed[3]);
}

// Kernel F: avg_probs, perplexity, loss finalization
__global__ void vq_final(const unsigned* __restrict__ hist,
                         const float* __restrict__ lossp,
                         float* __restrict__ out) {
    __shared__ float sP[K_CODES];
    __shared__ float sL[K_CODES];
    const int t = threadIdx.x;
    float p = (float)hist[t] * (1.0f / (float)N_ROWS);
    out[OUT_AVG + t] = p;
    sP[t] = p * logf(p + 1e-10f);
    sL[t] = (t < N_ROWS / BLK) ? lossp[t] : 0.f;
    __syncthreads();
    for (int o = 512; o > 0; o >>= 1) {
        if (t < o) { sP[t] += sP[t + o]; sL[t] += sL[t + o]; }
        __syncthreads();
    }
    if (t == 0) {
        out[OUT_PPL] = expf(-sP[0]);
        out[OUT_LOSS] = 0.25f * (sL[0] * (1.0f / (float)(N_ROWS * C_DIM)));
    }
}

extern "C" void kernel_launch(void* const* d_in, const int* in_sizes, int n_in,
                              void* d_out, int out_size, void* d_ws, size_t ws_size,
                              hipStream_t stream) {
    const float* x = (const float*)d_in[0];
    const float* emb = (const float*)d_in[1];
    float* out = (float*)d_out;
    float* ws_f = (float*)d_ws;
    unsigned* ws_u = (unsigned*)d_ws;
    int* ws_i = (int*)d_ws;
    unsigned short* bs = (unsigned short*)(ws_u + WS_BS_D);
    unsigned short* pi1 = (unsigned short*)(ws_u + WS_PI1);

    vq_prep<<<N_ROWS / BLK, BLK, 0, stream>>>(emb, ws_f + WS_EE, ws_u + WS_HIST,
                                              bs, ws_u + WS_QC);

    dim3 gM(N_ROWS / 128, 2);
    vq_mfma<<<gM, BLK, 0, stream>>>(x, bs, ws_f + WS_EE, ws_f + WS_PB1,
                                    ws_f + WS_PB2, pi1);

    vq_merge<<<N_ROWS / BLK, BLK, 0, stream>>>(ws_f + WS_PB1, ws_f + WS_PB2,
                                               pi1, ws_i + WS_IDX,
                                               ws_u + WS_QC, ws_i + WS_QROWS);

    vq_refine<<<1024, BLK, 0, stream>>>(x, emb, ws_f + WS_EE, ws_u + WS_QC,
                                        ws_i + WS_QROWS, ws_i + WS_IDX);

    vq_combine<<<N_ROWS / BLK, BLK, 0, stream>>>(x, emb, ws_i + WS_IDX,
                                                 ws_u + WS_HIST,
                                                 ws_f + WS_LOSSP, out);

    vq_final<<<1, K_CODES, 0, stream>>>(ws_u + WS_HIST, ws_f + WS_LOSSP, out);
}